// Round 1
// baseline (848.901 us; speedup 1.0000x reference)
//
#include <hip/hip_runtime.h>
#include <math.h>

#define NN   20000
#define NE   320000
#define ET   (NE + NN)
#define D_IN 256
#define DHID 512   // H * DH = H * DOUT

// ---------------- CSR build ----------------

__global__ __launch_bounds__(256) void init_count(int* count) {
    int i = blockIdx.x * 256 + threadIdx.x;
    if (i < NN) count[i] = 1;  // self-loop
}

__global__ __launch_bounds__(256) void hist_kernel(const int* __restrict__ dstv,
                                                   int* __restrict__ count) {
    int e = blockIdx.x * 256 + threadIdx.x;
    if (e < NE) atomicAdd(&count[dstv[e]], 1);
}

__global__ __launch_bounds__(1024) void scan_kernel(const int* __restrict__ count,
                                                    int* __restrict__ offs,
                                                    int* __restrict__ cursor) {
    __shared__ int sm[1024];
    const int CH = 20;  // 1024*20 >= NN
    int t = threadIdx.x;
    int base = t * CH;
    int local[CH];
    int s = 0;
#pragma unroll
    for (int i = 0; i < CH; i++) {
        int idx = base + i;
        int v = (idx < NN) ? count[idx] : 0;
        local[i] = s;
        s += v;
    }
    sm[t] = s;
    __syncthreads();
    for (int o = 1; o < 1024; o <<= 1) {
        int v = (t >= o) ? sm[t - o] : 0;
        __syncthreads();
        sm[t] += v;
        __syncthreads();
    }
    int pref = (t > 0) ? sm[t - 1] : 0;
#pragma unroll
    for (int i = 0; i < CH; i++) {
        int idx = base + i;
        if (idx < NN) {
            int o_ = pref + local[i];
            offs[idx] = o_;
            cursor[idx] = o_;
        }
    }
    if (t == 1023) offs[NN] = sm[1023];
}

__global__ __launch_bounds__(256) void scatter_kernel(const int* __restrict__ srcv,
                                                      const int* __restrict__ dstv,
                                                      int* __restrict__ cursor,
                                                      int* __restrict__ csr_src) {
    int e = blockIdx.x * 256 + threadIdx.x;
    if (e >= ET) return;
    int s, d;
    if (e < NE) { s = srcv[e]; d = dstv[e]; }
    else        { s = e - NE;  d = s; }
    int pos = atomicAdd(&cursor[d], 1);
    csr_src[pos] = s;
}

// ---------------- GEMM: out = A[M,K] @ W[K,512] + b ----------------
// blockIdx.y in [0,16): 0-7 -> (Wl,bl,outl) cols, 8-15 -> (Wr,br,outr)

__global__ __launch_bounds__(256) void gemm_lr(const float* __restrict__ A, int K,
                                               const float* __restrict__ Wl,
                                               const float* __restrict__ bl,
                                               float* __restrict__ outl,
                                               const float* __restrict__ Wr,
                                               const float* __restrict__ br,
                                               float* __restrict__ outr) {
    const int M = NN;
    int by = blockIdx.y;
    const float* __restrict__ W    = (by < 8) ? Wl : Wr;
    const float* __restrict__ bias = (by < 8) ? bl : br;
    float* __restrict__ outp       = (by < 8) ? outl : outr;
    int col0 = (by & 7) * 64;
    int row0 = blockIdx.x * 64;

    __shared__ float As[16][64];
    __shared__ float Bs[16][64];

    int t = threadIdx.x;
    int tx = t & 15, ty = t >> 4;
    int arow = t >> 2;
    int ak = (t & 3) << 2;
    int brow = t >> 4;
    int bcol = (t & 15) << 2;

    float acc[4][4] = {};

    for (int k0 = 0; k0 < K; k0 += 16) {
        float4 av = make_float4(0.f, 0.f, 0.f, 0.f);
        int gr = row0 + arow;
        if (gr < M) av = *(const float4*)&A[(long)gr * K + k0 + ak];
        As[ak + 0][arow] = av.x;
        As[ak + 1][arow] = av.y;
        As[ak + 2][arow] = av.z;
        As[ak + 3][arow] = av.w;
        *(float4*)&Bs[brow][bcol] = *(const float4*)&W[(long)(k0 + brow) * DHID + col0 + bcol];
        __syncthreads();
#pragma unroll
        for (int k = 0; k < 16; k++) {
            float4 a = *(const float4*)&As[k][ty << 2];
            float4 b = *(const float4*)&Bs[k][tx << 2];
            acc[0][0] += a.x * b.x; acc[0][1] += a.x * b.y; acc[0][2] += a.x * b.z; acc[0][3] += a.x * b.w;
            acc[1][0] += a.y * b.x; acc[1][1] += a.y * b.y; acc[1][2] += a.y * b.z; acc[1][3] += a.y * b.w;
            acc[2][0] += a.z * b.x; acc[2][1] += a.z * b.y; acc[2][2] += a.z * b.z; acc[2][3] += a.z * b.w;
            acc[3][0] += a.w * b.x; acc[3][1] += a.w * b.y; acc[3][2] += a.w * b.z; acc[3][3] += a.w * b.w;
        }
        __syncthreads();
    }

    float4 bv = *(const float4*)&bias[col0 + (tx << 2)];
#pragma unroll
    for (int i = 0; i < 4; i++) {
        int row = row0 + (ty << 2) + i;
        if (row < M) {
            float4 o;
            o.x = acc[i][0] + bv.x;
            o.y = acc[i][1] + bv.y;
            o.z = acc[i][2] + bv.z;
            o.w = acc[i][3] + bv.w;
            *(float4*)&outp[(long)row * DHID + col0 + (tx << 2)] = o;
        }
    }
}

// ---------------- fused per-node logits + online softmax + aggregate ----------------
// One block (256 thr) per dst node. Thread t owns channels 2t,2t+1 (head = t>>5).
// MODE 0: += bias then ELU (layer 1).  MODE 1: += bias (layer 2 final h).

template <int MODE>
__global__ __launch_bounds__(256) void aggregate_kernel(const float* __restrict__ l,
                                                        const float* __restrict__ r,
                                                        const float* __restrict__ att,
                                                        const float* __restrict__ bias,
                                                        const int* __restrict__ csr_src,
                                                        const int* __restrict__ offs,
                                                        float* __restrict__ out) {
    int i = blockIdx.x;
    int t = threadIdx.x;
    int c0 = t << 1;

    float2 ri = *(const float2*)&r[(long)i * DHID + c0];
    float2 at = *(const float2*)&att[c0];
    float2 bi = *(const float2*)&bias[c0];

    int beg = offs[i], end = offs[i + 1];
    float m = -3.0e38f, d = 0.f;
    float2 acc = make_float2(0.f, 0.f);

    for (int k = beg; k < end; k++) {
        int j = csr_src[k];
        float2 lj = *(const float2*)&l[(long)j * DHID + c0];
        float ex = lj.x + ri.x; ex = (ex > 0.f) ? ex : 0.2f * ex;
        float ey = lj.y + ri.y; ey = (ey > 0.f) ? ey : 0.2f * ey;
        float s = at.x * ex + at.y * ey;
        // reduce over the 32 lanes of this head group (masks <32 stay in-half)
#pragma unroll
        for (int o = 16; o; o >>= 1) s += __shfl_xor(s, o);
        if (s > m) {
            float sc = __expf(m - s);
            d *= sc; acc.x *= sc; acc.y *= sc;
            m = s;
        }
        float w = __expf(s - m);
        d += w;
        acc.x += w * lj.x;
        acc.y += w * lj.y;
    }
    float inv = 1.f / d;
    float ox = acc.x * inv + bi.x;
    float oy = acc.y * inv + bi.y;
    if (MODE == 0) {
        ox = (ox > 0.f) ? ox : expm1f(ox);
        oy = (oy > 0.f) ? oy : expm1f(oy);
    }
    *(float2*)&out[(long)i * DHID + c0] = make_float2(ox, oy);
}

// ---------------- log_softmax over 512 channels, one wave per row ----------------

__global__ __launch_bounds__(64) void logsoftmax_kernel(const float* __restrict__ h,
                                                        float* __restrict__ out) {
    int i = blockIdx.x;
    int t = threadIdx.x;
    float v[8];
    float m = -3.0e38f;
#pragma unroll
    for (int k = 0; k < 8; k++) {
        v[k] = h[(long)i * DHID + t + 64 * k];
        m = fmaxf(m, v[k]);
    }
#pragma unroll
    for (int o = 32; o; o >>= 1) m = fmaxf(m, __shfl_xor(m, o));
    float s = 0.f;
#pragma unroll
    for (int k = 0; k < 8; k++) s += __expf(v[k] - m);
#pragma unroll
    for (int o = 32; o; o >>= 1) s += __shfl_xor(s, o);
    float lg = logf(s);
#pragma unroll
    for (int k = 0; k < 8; k++) out[(long)i * DHID + t + 64 * k] = v[k] - m - lg;
}

// ---------------- launch ----------------

extern "C" void kernel_launch(void* const* d_in, const int* in_sizes, int n_in,
                              void* d_out, int out_size, void* d_ws, size_t ws_size,
                              hipStream_t stream) {
    const float* x     = (const float*)d_in[0];
    const int*   ei    = (const int*)d_in[1];
    const float* Wl1   = (const float*)d_in[2];
    const float* bl1   = (const float*)d_in[3];
    const float* Wr1   = (const float*)d_in[4];
    const float* br1   = (const float*)d_in[5];
    const float* att1  = (const float*)d_in[6];
    const float* bias1 = (const float*)d_in[7];
    const float* Wl2   = (const float*)d_in[8];
    const float* bl2   = (const float*)d_in[9];
    const float* Wr2   = (const float*)d_in[10];
    const float* br2   = (const float*)d_in[11];
    const float* att2  = (const float*)d_in[12];
    const float* bias2 = (const float*)d_in[13];

    float* out = (float*)d_out;
    float* h2  = out;                      // final layer-2 output [NN,512]
    float* lsm = out + (long)NN * DHID;    // log_softmax area; doubles as h1 scratch
    float* h1  = lsm;

    float* lbuf    = (float*)d_ws;                   // NN*512
    float* rbuf    = lbuf + (long)NN * DHID;         // NN*512
    int*   csr_src = (int*)(rbuf + (long)NN * DHID); // ET
    int*   count   = csr_src + ET;                   // NN
    int*   offs    = count + NN;                     // NN+1
    int*   cursor  = offs + NN + 1;                  // NN

    const int* srcv = ei;
    const int* dstv = ei + NE;

    // CSR by dst (shared by both layers)
    init_count<<<(NN + 255) / 256, 256, 0, stream>>>(count);
    hist_kernel<<<(NE + 255) / 256, 256, 0, stream>>>(dstv, count);
    scan_kernel<<<1, 1024, 0, stream>>>(count, offs, cursor);
    scatter_kernel<<<(ET + 255) / 256, 256, 0, stream>>>(srcv, dstv, cursor, csr_src);

    dim3 ggrid((NN + 63) / 64, 16);

    // layer 1
    gemm_lr<<<ggrid, 256, 0, stream>>>(x, D_IN, Wl1, bl1, lbuf, Wr1, br1, rbuf);
    aggregate_kernel<0><<<NN, 256, 0, stream>>>(lbuf, rbuf, att1, bias1, csr_src, offs, h1);

    // layer 2
    gemm_lr<<<ggrid, 256, 0, stream>>>(h1, DHID, Wl2, bl2, lbuf, Wr2, br2, rbuf);
    aggregate_kernel<1><<<NN, 256, 0, stream>>>(lbuf, rbuf, att2, bias2, csr_src, offs, h2);

    // log_softmax
    logsoftmax_kernel<<<NN, 64, 0, stream>>>(h2, lsm);
}

// Round 2
// 393.488 us; speedup vs baseline: 2.1574x; 2.1574x over previous
//
#include <hip/hip_runtime.h>
#include <math.h>

#define NN   20000
#define NE   320000
#define ET   (NE + NN)
#define D_IN 256
#define DHID 512    // H * DH = H * DOUT
#define NLR  1024   // combined l|r width
#define MPAD 20096  // 157 * 128

typedef __attribute__((ext_vector_type(8))) short bf16x8;
typedef __attribute__((ext_vector_type(4))) float f32x4;

typedef __attribute__((address_space(3))) uint       lds_uint;
typedef __attribute__((address_space(1))) const uint gbl_uint;
#define ASYNC16(gp, lp) \
    __builtin_amdgcn_global_load_lds((gbl_uint*)(gp), (lds_uint*)(lp), 16, 0, 0)

__device__ __forceinline__ ushort f2bf(float f) {
    uint u = __float_as_uint(f);
    return (ushort)((u + 0x7fffu + ((u >> 16) & 1u)) >> 16);
}

// ---------------- CSR build ----------------

__global__ __launch_bounds__(256) void init_count(int* count) {
    int i = blockIdx.x * 256 + threadIdx.x;
    if (i < NN) count[i] = 1;  // self-loop
}

__global__ __launch_bounds__(256) void hist_kernel(const int* __restrict__ dstv,
                                                   int* __restrict__ count) {
    int e = blockIdx.x * 256 + threadIdx.x;
    if (e < NE) atomicAdd(&count[dstv[e]], 1);
}

__global__ __launch_bounds__(1024) void scan_kernel(const int* __restrict__ count,
                                                    int* __restrict__ offs,
                                                    int* __restrict__ cursor) {
    __shared__ int sm[1024];
    const int CH = 20;
    int t = threadIdx.x;
    int base = t * CH;
    int local[CH];
    int s = 0;
#pragma unroll
    for (int i = 0; i < CH; i++) {
        int idx = base + i;
        int v = (idx < NN) ? count[idx] : 0;
        local[i] = s;
        s += v;
    }
    sm[t] = s;
    __syncthreads();
    for (int o = 1; o < 1024; o <<= 1) {
        int v = (t >= o) ? sm[t - o] : 0;
        __syncthreads();
        sm[t] += v;
        __syncthreads();
    }
    int pref = (t > 0) ? sm[t - 1] : 0;
#pragma unroll
    for (int i = 0; i < CH; i++) {
        int idx = base + i;
        if (idx < NN) {
            int o_ = pref + local[i];
            offs[idx] = o_;
            cursor[idx] = o_;
        }
    }
    if (t == 1023) offs[NN] = sm[1023];
}

__global__ __launch_bounds__(256) void scatter_kernel(const int* __restrict__ srcv,
                                                      const int* __restrict__ dstv,
                                                      int* __restrict__ cursor,
                                                      int* __restrict__ csr_src) {
    int e = blockIdx.x * 256 + threadIdx.x;
    if (e >= ET) return;
    int s, d;
    if (e < NE) { s = srcv[e]; d = dstv[e]; }
    else        { s = e - NE;  d = s; }
    int pos = atomicAdd(&cursor[d], 1);
    csr_src[pos] = s;
}

// ---------------- pre-passes: bf16 convert / transpose ----------------

// x [NN,256] f32 -> Abf [MPAD,256] bf16 (pad rows zeroed)
__global__ __launch_bounds__(256) void convert_x(const float* __restrict__ x,
                                                 ushort* __restrict__ a) {
    long e = ((long)blockIdx.x * 256 + threadIdx.x) * 4;
    if (e >= (long)MPAD * D_IN) return;
    int row = (int)(e >> 8);
    float4 v = make_float4(0.f, 0.f, 0.f, 0.f);
    if (row < NN) v = *(const float4*)&x[e];
    ushort4 o;
    o.x = f2bf(v.x); o.y = f2bf(v.y); o.z = f2bf(v.z); o.w = f2bf(v.w);
    *(ushort4*)&a[e] = o;
}

// zero pad rows [NN,MPAD) of the [MPAD,512] layer-2 A view
__global__ __launch_bounds__(256) void zero_pad2(ushort* __restrict__ a) {
    int t = blockIdx.x * 256 + threadIdx.x;
    if (t < (MPAD - NN) * DHID / 4) {
        ushort4 z = {0, 0, 0, 0};
        *(ushort4*)&a[(long)NN * DHID + (long)t * 4] = z;
    }
}

// Wl,Wr [K,512] f32 -> Wt [1024,K] bf16 (rows 0-511 = Wl^T, 512-1023 = Wr^T)
__global__ __launch_bounds__(256) void transpose_w(const float* __restrict__ Wl,
                                                   const float* __restrict__ Wr,
                                                   ushort* __restrict__ Wt, int K) {
    __shared__ float tile[32][33];
    int k0 = blockIdx.x * 32, n0 = blockIdx.y * 32;
    int tx = threadIdx.x & 31, ty = threadIdx.x >> 5;
    const float* __restrict__ W = (n0 < DHID) ? Wl : Wr;
    int nb = (n0 < DHID) ? n0 : n0 - DHID;
#pragma unroll
    for (int r = ty; r < 32; r += 8)
        tile[r][tx] = W[(long)(k0 + r) * DHID + nb + tx];
    __syncthreads();
#pragma unroll
    for (int r = ty; r < 32; r += 8)
        Wt[(long)(n0 + r) * K + k0 + tx] = f2bf(tile[tx][r]);
}

// ---------------- bf16 MFMA GEMM: out[M,1024] = A[M,K] @ Wt^T + (bl|br) ----------------
// BM=BN=128, BK=64; 4 waves (2x2), each 64x64 via 4x4 frags of 16x16x32.
// LDS layout [128 rows][64 k] bf16, 16B-chunk XOR swizzle: phys = log ^ (row&7)
// applied on the *global source* for global_load_lds (linear dest) and on reads.

#define BM 128
#define BN 128
#define BK 64

__global__ __launch_bounds__(256) void gemm_mfma(const ushort* __restrict__ A, int K,
                                                 const ushort* __restrict__ Wt,
                                                 const float* __restrict__ bl,
                                                 const float* __restrict__ br,
                                                 ushort* __restrict__ out) {
    __shared__ ushort As[BM * BK];
    __shared__ ushort Bs[BN * BK];

    int t = threadIdx.x;
    int row0 = blockIdx.x * BM;
    int col0 = blockIdx.y * BN;

    int lane = t & 63, w = t >> 6;
    int wr = w >> 1, wc = w & 1;
    int l16 = lane & 15, lhi = lane >> 4;

    f32x4 acc[4][4];
#pragma unroll
    for (int m = 0; m < 4; m++)
#pragma unroll
        for (int n = 0; n < 4; n++)
            acc[m][n] = (f32x4){0.f, 0.f, 0.f, 0.f};

    for (int k0 = 0; k0 < K; k0 += BK) {
#pragma unroll
        for (int q = 0; q < 4; q++) {
            int chunk = q * 256 + t;          // 16B chunk index in tile
            int row = chunk >> 3;             // 8 chunks (64 bf16) per row
            int il = (chunk & 7) ^ (row & 7); // pre-swizzled source chunk
            ASYNC16(A  + (long)(row0 + row) * K + k0 + il * 8, (char*)As + chunk * 16);
            ASYNC16(Wt + (long)(col0 + row) * K + k0 + il * 8, (char*)Bs + chunk * 16);
        }
        __syncthreads();  // drains vmcnt -> staged data visible
#pragma unroll
        for (int kk = 0; kk < 2; kk++) {
            bf16x8 af[4], bfr[4];
#pragma unroll
            for (int m = 0; m < 4; m++) {
                int rl = wr * 64 + m * 16 + l16;
                int off = rl * 128 + ((kk * 64 + lhi * 16) ^ ((rl & 7) << 4));
                af[m] = *(const bf16x8*)((const char*)As + off);
            }
#pragma unroll
            for (int n = 0; n < 4; n++) {
                int rl = wc * 64 + n * 16 + l16;
                int off = rl * 128 + ((kk * 64 + lhi * 16) ^ ((rl & 7) << 4));
                bfr[n] = *(const bf16x8*)((const char*)Bs + off);
            }
#pragma unroll
            for (int m = 0; m < 4; m++)
#pragma unroll
                for (int n = 0; n < 4; n++)
                    acc[m][n] = __builtin_amdgcn_mfma_f32_16x16x32_bf16(af[m], bfr[n], acc[m][n], 0, 0, 0);
        }
        __syncthreads();
    }

    float bvn[4];
#pragma unroll
    for (int n = 0; n < 4; n++) {
        int col = col0 + wc * 64 + n * 16 + l16;
        bvn[n] = (col < DHID) ? bl[col] : br[col - DHID];
    }
#pragma unroll
    for (int m = 0; m < 4; m++) {
        int rbase = row0 + wr * 64 + m * 16 + lhi * 4;
#pragma unroll
        for (int j = 0; j < 4; j++) {
            int row = rbase + j;
            if (row < NN) {
#pragma unroll
                for (int n = 0; n < 4; n++) {
                    int col = col0 + wc * 64 + n * 16 + l16;
                    out[(long)row * NLR + col] = f2bf(acc[m][n][j] + bvn[n]);
                }
            }
        }
    }
}

// ---------------- fused per-node logits + online softmax + aggregate ----------------
// One block (256 thr) per dst node; thread t owns channels 2t,2t+1 (head = t>>5).
// lr is bf16 [NN,1024]: l = cols 0-511, r = cols 512-1023.
// MODE 0: +bias, ELU, write bf16 (h1 -> layer-2 A buffer, stride 512).
// MODE 1: +bias, write f32 (final h2).

template <int MODE>
__global__ __launch_bounds__(256) void aggregate_kernel(const ushort* __restrict__ lr,
                                                        const float* __restrict__ att,
                                                        const float* __restrict__ bias,
                                                        const int* __restrict__ csr_src,
                                                        const int* __restrict__ offs,
                                                        ushort* __restrict__ out_bf,
                                                        float* __restrict__ out_f32) {
    int i = blockIdx.x;
    int t = threadIdx.x;
    int c0 = t << 1;

    uint ur = *(const uint*)(lr + (long)i * NLR + DHID + c0);
    float rx = __uint_as_float(ur << 16);
    float ry = __uint_as_float(ur & 0xffff0000u);
    float2 at = *(const float2*)&att[c0];
    float2 bi = *(const float2*)&bias[c0];

    int beg = offs[i], end = offs[i + 1];
    float m = -3.0e38f, d = 0.f, ax = 0.f, ay = 0.f;

    for (int k = beg; k < end; k++) {
        int j = csr_src[k];
        uint ul = *(const uint*)(lr + (long)j * NLR + c0);
        float lx = __uint_as_float(ul << 16);
        float ly = __uint_as_float(ul & 0xffff0000u);
        float ex = lx + rx; ex = (ex > 0.f) ? ex : 0.2f * ex;
        float ey = ly + ry; ey = (ey > 0.f) ? ey : 0.2f * ey;
        float s = at.x * ex + at.y * ey;
#pragma unroll
        for (int o = 16; o; o >>= 1) s += __shfl_xor(s, o);
        if (s > m) {
            float sc = __expf(m - s);
            d *= sc; ax *= sc; ay *= sc;
            m = s;
        }
        float wgt = __expf(s - m);
        d += wgt;
        ax += wgt * lx;
        ay += wgt * ly;
    }
    float inv = 1.f / d;
    float ox = ax * inv + bi.x;
    float oy = ay * inv + bi.y;
    if (MODE == 0) {
        ox = (ox > 0.f) ? ox : expm1f(ox);
        oy = (oy > 0.f) ? oy : expm1f(oy);
        uint pv = (uint)f2bf(ox) | ((uint)f2bf(oy) << 16);
        *(uint*)(out_bf + (long)i * DHID + c0) = pv;
    } else {
        *(float2*)&out_f32[(long)i * DHID + c0] = make_float2(ox, oy);
    }
}

// ---------------- log_softmax over 512 channels, one wave per row ----------------

__global__ __launch_bounds__(64) void logsoftmax_kernel(const float* __restrict__ h,
                                                        float* __restrict__ out) {
    int i = blockIdx.x;
    int t = threadIdx.x;
    float v[8];
    float m = -3.0e38f;
#pragma unroll
    for (int k = 0; k < 8; k++) {
        v[k] = h[(long)i * DHID + t + 64 * k];
        m = fmaxf(m, v[k]);
    }
#pragma unroll
    for (int o = 32; o; o >>= 1) m = fmaxf(m, __shfl_xor(m, o));
    float s = 0.f;
#pragma unroll
    for (int k = 0; k < 8; k++) s += __expf(v[k] - m);
#pragma unroll
    for (int o = 32; o; o >>= 1) s += __shfl_xor(s, o);
    float lg = logf(s);
#pragma unroll
    for (int k = 0; k < 8; k++) out[(long)i * DHID + t + 64 * k] = v[k] - m - lg;
}

// ---------------- launch ----------------

extern "C" void kernel_launch(void* const* d_in, const int* in_sizes, int n_in,
                              void* d_out, int out_size, void* d_ws, size_t ws_size,
                              hipStream_t stream) {
    const float* x     = (const float*)d_in[0];
    const int*   ei    = (const int*)d_in[1];
    const float* Wl1   = (const float*)d_in[2];
    const float* bl1   = (const float*)d_in[3];
    const float* Wr1   = (const float*)d_in[4];
    const float* br1   = (const float*)d_in[5];
    const float* att1  = (const float*)d_in[6];
    const float* bias1 = (const float*)d_in[7];
    const float* Wl2   = (const float*)d_in[8];
    const float* bl2   = (const float*)d_in[9];
    const float* Wr2   = (const float*)d_in[10];
    const float* br2   = (const float*)d_in[11];
    const float* att2  = (const float*)d_in[12];
    const float* bias2 = (const float*)d_in[13];

    float* out = (float*)d_out;
    float* h2  = out;                      // final layer-2 output [NN,512] f32
    float* lsm = out + (long)NN * DHID;    // log_softmax area

    // workspace layout (all 4B-aligned)
    ushort* lrbuf  = (ushort*)d_ws;                      // [NN,1024] bf16
    ushort* Abf    = lrbuf + (long)NN * NLR;             // [MPAD,512] bf16 (layer1 uses [MPAD,256])
    ushort* Wt1    = Abf + (long)MPAD * DHID;            // [1024,256] bf16
    ushort* Wt2    = Wt1 + (long)NLR * D_IN;             // [1024,512] bf16
    int*    csr_src = (int*)(Wt2 + (long)NLR * DHID);    // ET
    int*    count   = csr_src + ET;                      // NN
    int*    offs    = count + NN;                        // NN+1
    int*    cursor  = offs + NN + 1;                     // NN

    const int* srcv = ei;
    const int* dstv = ei + NE;

    // pre-passes
    convert_x<<<(MPAD * D_IN / 4 + 255) / 256, 256, 0, stream>>>(x, Abf);
    zero_pad2<<<((MPAD - NN) * DHID / 4 + 255) / 256, 256, 0, stream>>>(Abf);
    transpose_w<<<dim3(D_IN / 32, NLR / 32), 256, 0, stream>>>(Wl1, Wr1, Wt1, D_IN);
    transpose_w<<<dim3(DHID / 32, NLR / 32), 256, 0, stream>>>(Wl2, Wr2, Wt2, DHID);

    // CSR by dst (shared by both layers)
    init_count<<<(NN + 255) / 256, 256, 0, stream>>>(count);
    hist_kernel<<<(NE + 255) / 256, 256, 0, stream>>>(dstv, count);
    scan_kernel<<<1, 1024, 0, stream>>>(count, offs, cursor);
    scatter_kernel<<<(ET + 255) / 256, 256, 0, stream>>>(srcv, dstv, cursor, csr_src);

    dim3 ggrid((NN + BM - 1) / BM, NLR / BN);

    // layer 1
    gemm_mfma<<<ggrid, 256, 0, stream>>>(Abf, D_IN, Wt1, bl1, br1, lrbuf);
    aggregate_kernel<0><<<NN, 256, 0, stream>>>(lrbuf, att1, bias1, csr_src, offs, Abf, nullptr);

    // layer 2 (h1 already bf16 in Abf, pads zeroed)
    gemm_mfma<<<ggrid, 256, 0, stream>>>(Abf, DHID, Wt2, bl2, br2, lrbuf);
    aggregate_kernel<1><<<NN, 256, 0, stream>>>(lrbuf, att2, bias2, csr_src, offs, nullptr, h2);

    // log_softmax
    logsoftmax_kernel<<<NN, 64, 0, stream>>>(h2, lsm);
}

// Round 3
// 270.047 us; speedup vs baseline: 3.1435x; 1.4571x over previous
//
#include <hip/hip_runtime.h>
#include <math.h>

#define NN   20000
#define NE   320000
#define ET   (NE + NN)
#define D_IN 256
#define DHID 512    // H * DH = H * DOUT
#define NLR  1024   // combined l|r width
#define MPAD 20096  // 157 * 128

typedef __attribute__((ext_vector_type(8))) short bf16x8;
typedef __attribute__((ext_vector_type(4))) float f32x4;

typedef __attribute__((address_space(3))) uint       lds_uint;
typedef __attribute__((address_space(1))) const uint gbl_uint;
#define ASYNC16(gp, lp) \
    __builtin_amdgcn_global_load_lds((gbl_uint*)(gp), (lds_uint*)(lp), 16, 0, 0)

__device__ __forceinline__ ushort f2bf(float f) {
    uint u = __float_as_uint(f);
    return (ushort)((u + 0x7fffu + ((u >> 16) & 1u)) >> 16);
}

// ---------------- CSR build ----------------

__global__ __launch_bounds__(256) void init_count(int* count) {
    int i = blockIdx.x * 256 + threadIdx.x;
    if (i < NN) count[i] = 1;  // self-loop
}

__global__ __launch_bounds__(256) void hist_kernel(const int* __restrict__ dstv,
                                                   int* __restrict__ count) {
    int e = blockIdx.x * 256 + threadIdx.x;
    if (e < NE) atomicAdd(&count[dstv[e]], 1);
}

__global__ __launch_bounds__(1024) void scan_kernel(const int* __restrict__ count,
                                                    int* __restrict__ offs,
                                                    int* __restrict__ cursor) {
    __shared__ int sm[1024];
    const int CH = 20;
    int t = threadIdx.x;
    int base = t * CH;
    int local[CH];
    int s = 0;
#pragma unroll
    for (int i = 0; i < CH; i++) {
        int idx = base + i;
        int v = (idx < NN) ? count[idx] : 0;
        local[i] = s;
        s += v;
    }
    sm[t] = s;
    __syncthreads();
    for (int o = 1; o < 1024; o <<= 1) {
        int v = (t >= o) ? sm[t - o] : 0;
        __syncthreads();
        sm[t] += v;
        __syncthreads();
    }
    int pref = (t > 0) ? sm[t - 1] : 0;
#pragma unroll
    for (int i = 0; i < CH; i++) {
        int idx = base + i;
        if (idx < NN) {
            int o_ = pref + local[i];
            offs[idx] = o_;
            cursor[idx] = o_;
        }
    }
    if (t == 1023) offs[NN] = sm[1023];
}

__global__ __launch_bounds__(256) void scatter_kernel(const int* __restrict__ srcv,
                                                      const int* __restrict__ dstv,
                                                      int* __restrict__ cursor,
                                                      int* __restrict__ csr_src) {
    int e = blockIdx.x * 256 + threadIdx.x;
    if (e >= ET) return;
    int s, d;
    if (e < NE) { s = srcv[e]; d = dstv[e]; }
    else        { s = e - NE;  d = s; }
    int pos = atomicAdd(&cursor[d], 1);
    csr_src[pos] = s;
}

// ---------------- pre-passes: bf16 convert / transpose ----------------

__global__ __launch_bounds__(256) void convert_x(const float* __restrict__ x,
                                                 ushort* __restrict__ a) {
    long e = ((long)blockIdx.x * 256 + threadIdx.x) * 4;
    if (e >= (long)MPAD * D_IN) return;
    int row = (int)(e >> 8);
    float4 v = make_float4(0.f, 0.f, 0.f, 0.f);
    if (row < NN) v = *(const float4*)&x[e];
    ushort4 o;
    o.x = f2bf(v.x); o.y = f2bf(v.y); o.z = f2bf(v.z); o.w = f2bf(v.w);
    *(ushort4*)&a[e] = o;
}

__global__ __launch_bounds__(256) void zero_pad2(ushort* __restrict__ a) {
    int t = blockIdx.x * 256 + threadIdx.x;
    if (t < (MPAD - NN) * DHID / 4) {
        ushort4 z = {0, 0, 0, 0};
        *(ushort4*)&a[(long)NN * DHID + (long)t * 4] = z;
    }
}

__global__ __launch_bounds__(256) void transpose_w(const float* __restrict__ Wl,
                                                   const float* __restrict__ Wr,
                                                   ushort* __restrict__ Wt, int K) {
    __shared__ float tile[32][33];
    int k0 = blockIdx.x * 32, n0 = blockIdx.y * 32;
    int tx = threadIdx.x & 31, ty = threadIdx.x >> 5;
    const float* __restrict__ W = (n0 < DHID) ? Wl : Wr;
    int nb = (n0 < DHID) ? n0 : n0 - DHID;
#pragma unroll
    for (int r = ty; r < 32; r += 8)
        tile[r][tx] = W[(long)(k0 + r) * DHID + nb + tx];
    __syncthreads();
#pragma unroll
    for (int r = ty; r < 32; r += 8)
        Wt[(long)(n0 + r) * K + k0 + tx] = f2bf(tile[tx][r]);
}

// ---------------- bf16 MFMA GEMM: out[M,1024] = A[M,K] @ Wt^T + (bl|br) ----------------

#define BM 128
#define BN 128
#define BK 64

__global__ __launch_bounds__(256) void gemm_mfma(const ushort* __restrict__ A, int K,
                                                 const ushort* __restrict__ Wt,
                                                 const float* __restrict__ bl,
                                                 const float* __restrict__ br,
                                                 ushort* __restrict__ out) {
    __shared__ ushort As[BM * BK];
    __shared__ ushort Bs[BN * BK];

    int t = threadIdx.x;
    int row0 = blockIdx.x * BM;
    int col0 = blockIdx.y * BN;

    int lane = t & 63, w = t >> 6;
    int wr = w >> 1, wc = w & 1;
    int l16 = lane & 15, lhi = lane >> 4;

    f32x4 acc[4][4];
#pragma unroll
    for (int m = 0; m < 4; m++)
#pragma unroll
        for (int n = 0; n < 4; n++)
            acc[m][n] = (f32x4){0.f, 0.f, 0.f, 0.f};

    for (int k0 = 0; k0 < K; k0 += BK) {
#pragma unroll
        for (int q = 0; q < 4; q++) {
            int chunk = q * 256 + t;
            int row = chunk >> 3;
            int il = (chunk & 7) ^ (row & 7);
            ASYNC16(A  + (long)(row0 + row) * K + k0 + il * 8, (char*)As + chunk * 16);
            ASYNC16(Wt + (long)(col0 + row) * K + k0 + il * 8, (char*)Bs + chunk * 16);
        }
        __syncthreads();
#pragma unroll
        for (int kk = 0; kk < 2; kk++) {
            bf16x8 af[4], bfr[4];
#pragma unroll
            for (int m = 0; m < 4; m++) {
                int rl = wr * 64 + m * 16 + l16;
                int off = rl * 128 + ((kk * 64 + lhi * 16) ^ ((rl & 7) << 4));
                af[m] = *(const bf16x8*)((const char*)As + off);
            }
#pragma unroll
            for (int n = 0; n < 4; n++) {
                int rl = wc * 64 + n * 16 + l16;
                int off = rl * 128 + ((kk * 64 + lhi * 16) ^ ((rl & 7) << 4));
                bfr[n] = *(const bf16x8*)((const char*)Bs + off);
            }
#pragma unroll
            for (int m = 0; m < 4; m++)
#pragma unroll
                for (int n = 0; n < 4; n++)
                    acc[m][n] = __builtin_amdgcn_mfma_f32_16x16x32_bf16(af[m], bfr[n], acc[m][n], 0, 0, 0);
        }
        __syncthreads();
    }

    float bvn[4];
#pragma unroll
    for (int n = 0; n < 4; n++) {
        int col = col0 + wc * 64 + n * 16 + l16;
        bvn[n] = (col < DHID) ? bl[col] : br[col - DHID];
    }
#pragma unroll
    for (int m = 0; m < 4; m++) {
        int rbase = row0 + wr * 64 + m * 16 + lhi * 4;
#pragma unroll
        for (int j = 0; j < 4; j++) {
            int row = rbase + j;
            if (row < NN) {
#pragma unroll
                for (int n = 0; n < 4; n++) {
                    int col = col0 + wc * 64 + n * 16 + l16;
                    out[(long)row * NLR + col] = f2bf(acc[m][n][j] + bvn[n]);
                }
            }
        }
    }
}

// ---------------- fused per-node logits + online softmax + aggregate ----------------
// One WAVE per dst node (4 nodes per 256-thr block). Lane owns channels
// lane*8 .. lane*8+7; head = lane>>3 (8 lanes/head). Head-reduce = 3 shfl_xor.
// Softmax in exp2 domain (logit pre-scaled by log2e; softmax invariant).
// MODE 0: +bias, ELU, write bf16 (h1). MODE 1: +bias, write f32 (h2).

#define CVT8(u, f)                                  \
    f[0] = __uint_as_float((u).x << 16);            \
    f[1] = __uint_as_float((u).x & 0xffff0000u);    \
    f[2] = __uint_as_float((u).y << 16);            \
    f[3] = __uint_as_float((u).y & 0xffff0000u);    \
    f[4] = __uint_as_float((u).z << 16);            \
    f[5] = __uint_as_float((u).z & 0xffff0000u);    \
    f[6] = __uint_as_float((u).w << 16);            \
    f[7] = __uint_as_float((u).w & 0xffff0000u);

template <int MODE>
__global__ __launch_bounds__(256) void aggregate_kernel(const ushort* __restrict__ lr,
                                                        const float* __restrict__ att,
                                                        const float* __restrict__ bias,
                                                        const int* __restrict__ csr_src,
                                                        const int* __restrict__ offs,
                                                        ushort* __restrict__ out_bf,
                                                        float* __restrict__ out_f32) {
    int i = blockIdx.x * 4 + (threadIdx.x >> 6);
    int lane = threadIdx.x & 63;
    int c0 = lane << 3;

    uint4 ur = *(const uint4*)(lr + (long)i * NLR + DHID + c0);
    float rv[8];
    CVT8(ur, rv);
    float av[8];
    *(float4*)&av[0] = *(const float4*)&att[c0];
    *(float4*)&av[4] = *(const float4*)&att[c0 + 4];

    int beg = offs[i], end = offs[i + 1];
    float m = -3.0e38f, d = 0.f;
    float acc[8] = {0.f, 0.f, 0.f, 0.f, 0.f, 0.f, 0.f, 0.f};

    int j = csr_src[beg];
    uint4 v = *(const uint4*)(lr + (long)j * NLR + c0);

    for (int k = beg; k < end; k++) {
        uint4 vc = v;
        int kn = (k + 1 < end) ? k + 1 : k;
        int jn = csr_src[kn];
        v = *(const uint4*)(lr + (long)jn * NLR + c0);

        float lx[8];
        CVT8(vc, lx);
        float s = 0.f;
#pragma unroll
        for (int c = 0; c < 8; c++) {
            float e = lx[c] + rv[c];
            e = fmaxf(e, 0.2f * e);          // leaky_relu, branchless
            s = fmaf(av[c], e, s);
        }
        s *= 1.44269504f;                    // exp2 domain
        s += __shfl_xor(s, 1);
        s += __shfl_xor(s, 2);
        s += __shfl_xor(s, 4);

        if (s > m) {
            float sc = exp2f(m - s);
            d *= sc;
#pragma unroll
            for (int c = 0; c < 8; c++) acc[c] *= sc;
            m = s;
        }
        float wgt = exp2f(s - m);
        d += wgt;
#pragma unroll
        for (int c = 0; c < 8; c++) acc[c] = fmaf(wgt, lx[c], acc[c]);
    }

    float inv = 1.f / d;
    float o[8];
#pragma unroll
    for (int c = 0; c < 8; c++) o[c] = fmaf(acc[c], inv, bias[c0 + c]);

    if (MODE == 0) {
#pragma unroll
        for (int c = 0; c < 8; c++) o[c] = (o[c] > 0.f) ? o[c] : expm1f(o[c]);
        uint4 p;
        p.x = (uint)f2bf(o[0]) | ((uint)f2bf(o[1]) << 16);
        p.y = (uint)f2bf(o[2]) | ((uint)f2bf(o[3]) << 16);
        p.z = (uint)f2bf(o[4]) | ((uint)f2bf(o[5]) << 16);
        p.w = (uint)f2bf(o[6]) | ((uint)f2bf(o[7]) << 16);
        *(uint4*)(out_bf + (long)i * DHID + c0) = p;
    } else {
        *(float4*)&out_f32[(long)i * DHID + c0] = *(float4*)&o[0];
        *(float4*)&out_f32[(long)i * DHID + c0 + 4] = *(float4*)&o[4];
    }
}

// ---------------- log_softmax over 512 channels, one wave per row ----------------

__global__ __launch_bounds__(64) void logsoftmax_kernel(const float* __restrict__ h,
                                                        float* __restrict__ out) {
    int i = blockIdx.x;
    int t = threadIdx.x;
    float v[8];
    float m = -3.0e38f;
#pragma unroll
    for (int k = 0; k < 8; k++) {
        v[k] = h[(long)i * DHID + t + 64 * k];
        m = fmaxf(m, v[k]);
    }
#pragma unroll
    for (int o = 32; o; o >>= 1) m = fmaxf(m, __shfl_xor(m, o));
    float s = 0.f;
#pragma unroll
    for (int k = 0; k < 8; k++) s += __expf(v[k] - m);
#pragma unroll
    for (int o = 32; o; o >>= 1) s += __shfl_xor(s, o);
    float lg = logf(s);
#pragma unroll
    for (int k = 0; k < 8; k++) out[(long)i * DHID + t + 64 * k] = v[k] - m - lg;
}

// ---------------- launch ----------------

extern "C" void kernel_launch(void* const* d_in, const int* in_sizes, int n_in,
                              void* d_out, int out_size, void* d_ws, size_t ws_size,
                              hipStream_t stream) {
    const float* x     = (const float*)d_in[0];
    const int*   ei    = (const int*)d_in[1];
    const float* Wl1   = (const float*)d_in[2];
    const float* bl1   = (const float*)d_in[3];
    const float* Wr1   = (const float*)d_in[4];
    const float* br1   = (const float*)d_in[5];
    const float* att1  = (const float*)d_in[6];
    const float* bias1 = (const float*)d_in[7];
    const float* Wl2   = (const float*)d_in[8];
    const float* bl2   = (const float*)d_in[9];
    const float* Wr2   = (const float*)d_in[10];
    const float* br2   = (const float*)d_in[11];
    const float* att2  = (const float*)d_in[12];
    const float* bias2 = (const float*)d_in[13];

    float* out = (float*)d_out;
    float* h2  = out;                      // final layer-2 output [NN,512] f32
    float* lsm = out + (long)NN * DHID;    // log_softmax area

    ushort* lrbuf  = (ushort*)d_ws;                      // [NN,1024] bf16
    ushort* Abf    = lrbuf + (long)NN * NLR;             // [MPAD,512] bf16
    ushort* Wt1    = Abf + (long)MPAD * DHID;            // [1024,256] bf16
    ushort* Wt2    = Wt1 + (long)NLR * D_IN;             // [1024,512] bf16
    int*    csr_src = (int*)(Wt2 + (long)NLR * DHID);    // ET
    int*    count   = csr_src + ET;                      // NN
    int*    offs    = count + NN;                        // NN+1
    int*    cursor  = offs + NN + 1;                     // NN

    const int* srcv = ei;
    const int* dstv = ei + NE;

    convert_x<<<(MPAD * D_IN / 4 + 255) / 256, 256, 0, stream>>>(x, Abf);
    zero_pad2<<<((MPAD - NN) * DHID / 4 + 255) / 256, 256, 0, stream>>>(Abf);
    transpose_w<<<dim3(D_IN / 32, NLR / 32), 256, 0, stream>>>(Wl1, Wr1, Wt1, D_IN);
    transpose_w<<<dim3(DHID / 32, NLR / 32), 256, 0, stream>>>(Wl2, Wr2, Wt2, DHID);

    init_count<<<(NN + 255) / 256, 256, 0, stream>>>(count);
    hist_kernel<<<(NE + 255) / 256, 256, 0, stream>>>(dstv, count);
    scan_kernel<<<1, 1024, 0, stream>>>(count, offs, cursor);
    scatter_kernel<<<(ET + 255) / 256, 256, 0, stream>>>(srcv, dstv, cursor, csr_src);

    dim3 ggrid((NN + BM - 1) / BM, NLR / BN);

    // layer 1
    gemm_mfma<<<ggrid, 256, 0, stream>>>(Abf, D_IN, Wt1, bl1, br1, lrbuf);
    aggregate_kernel<0><<<NN / 4, 256, 0, stream>>>(lrbuf, att1, bias1, csr_src, offs, Abf, nullptr);

    // layer 2
    gemm_mfma<<<ggrid, 256, 0, stream>>>(Abf, DHID, Wt2, bl2, br2, lrbuf);
    aggregate_kernel<1><<<NN / 4, 256, 0, stream>>>(lrbuf, att2, bias2, csr_src, offs, nullptr, h2);

    // log_softmax
    logsoftmax_kernel<<<NN, 64, 0, stream>>>(h2, lsm);
}

// Round 4
// 262.844 us; speedup vs baseline: 3.2297x; 1.0274x over previous
//
#include <hip/hip_runtime.h>
#include <math.h>

#define NN   20000
#define NE   320000
#define ET   (NE + NN)
#define D_IN 256
#define DHID 512    // H * DH = H * DOUT
#define NLR  1024   // combined l|r width
#define MPAD 20096  // 157 * 128

typedef __attribute__((ext_vector_type(8))) short bf16x8;
typedef __attribute__((ext_vector_type(4))) float f32x4;

typedef __attribute__((address_space(3))) uint       lds_uint;
typedef __attribute__((address_space(1))) const uint gbl_uint;
#define ASYNC16(gp, lp) \
    __builtin_amdgcn_global_load_lds((gbl_uint*)(gp), (lds_uint*)(lp), 16, 0, 0)

__device__ __forceinline__ ushort f2bf(float f) {
    uint u = __float_as_uint(f);
    return (ushort)((u + 0x7fffu + ((u >> 16) & 1u)) >> 16);
}

// ---------------- CSR build ----------------

__global__ __launch_bounds__(256) void init_count(int* count) {
    int i = blockIdx.x * 256 + threadIdx.x;
    if (i < NN) count[i] = 1;  // self-loop
}

__global__ __launch_bounds__(256) void hist_kernel(const int* __restrict__ dstv,
                                                   int* __restrict__ count) {
    int e = blockIdx.x * 256 + threadIdx.x;
    if (e < NE) atomicAdd(&count[dstv[e]], 1);
}

__global__ __launch_bounds__(1024) void scan_kernel(const int* __restrict__ count,
                                                    int* __restrict__ offs,
                                                    int* __restrict__ cursor) {
    __shared__ int sm[1024];
    const int CH = 20;
    int t = threadIdx.x;
    int base = t * CH;
    int local[CH];
    int s = 0;
#pragma unroll
    for (int i = 0; i < CH; i++) {
        int idx = base + i;
        int v = (idx < NN) ? count[idx] : 0;
        local[i] = s;
        s += v;
    }
    sm[t] = s;
    __syncthreads();
    for (int o = 1; o < 1024; o <<= 1) {
        int v = (t >= o) ? sm[t - o] : 0;
        __syncthreads();
        sm[t] += v;
        __syncthreads();
    }
    int pref = (t > 0) ? sm[t - 1] : 0;
#pragma unroll
    for (int i = 0; i < CH; i++) {
        int idx = base + i;
        if (idx < NN) {
            int o_ = pref + local[i];
            offs[idx] = o_;
            cursor[idx] = o_;
        }
    }
    if (t == 1023) offs[NN] = sm[1023];
}

__global__ __launch_bounds__(256) void scatter_kernel(const int* __restrict__ srcv,
                                                      const int* __restrict__ dstv,
                                                      int* __restrict__ cursor,
                                                      int* __restrict__ csr_src) {
    int e = blockIdx.x * 256 + threadIdx.x;
    if (e >= ET) return;
    int s, d;
    if (e < NE) { s = srcv[e]; d = dstv[e]; }
    else        { s = e - NE;  d = s; }
    int pos = atomicAdd(&cursor[d], 1);
    csr_src[pos] = s;
}

// ---------------- pre-passes: bf16 convert / transpose ----------------

__global__ __launch_bounds__(256) void convert_x(const float* __restrict__ x,
                                                 ushort* __restrict__ a) {
    long e = ((long)blockIdx.x * 256 + threadIdx.x) * 4;
    if (e >= (long)MPAD * D_IN) return;
    int row = (int)(e >> 8);
    float4 v = make_float4(0.f, 0.f, 0.f, 0.f);
    if (row < NN) v = *(const float4*)&x[e];
    ushort4 o;
    o.x = f2bf(v.x); o.y = f2bf(v.y); o.z = f2bf(v.z); o.w = f2bf(v.w);
    *(ushort4*)&a[e] = o;
}

__global__ __launch_bounds__(256) void zero_pad2(ushort* __restrict__ a) {
    int t = blockIdx.x * 256 + threadIdx.x;
    if (t < (MPAD - NN) * DHID / 4) {
        ushort4 z = {0, 0, 0, 0};
        *(ushort4*)&a[(long)NN * DHID + (long)t * 4] = z;
    }
}

__global__ __launch_bounds__(256) void transpose_w(const float* __restrict__ Wl,
                                                   const float* __restrict__ Wr,
                                                   ushort* __restrict__ Wt, int K) {
    __shared__ float tile[32][33];
    int k0 = blockIdx.x * 32, n0 = blockIdx.y * 32;
    int tx = threadIdx.x & 31, ty = threadIdx.x >> 5;
    const float* __restrict__ W = (n0 < DHID) ? Wl : Wr;
    int nb = (n0 < DHID) ? n0 : n0 - DHID;
#pragma unroll
    for (int r = ty; r < 32; r += 8)
        tile[r][tx] = W[(long)(k0 + r) * DHID + nb + tx];
    __syncthreads();
#pragma unroll
    for (int r = ty; r < 32; r += 8)
        Wt[(long)(n0 + r) * K + k0 + tx] = f2bf(tile[tx][r]);
}

// ---------------- bf16 MFMA GEMM: out[M,1024] = A[M,K] @ Wt^T + (bl|br) ----------------

#define BM 128
#define BN 128
#define BK 64

__global__ __launch_bounds__(256) void gemm_mfma(const ushort* __restrict__ A, int K,
                                                 const ushort* __restrict__ Wt,
                                                 const float* __restrict__ bl,
                                                 const float* __restrict__ br,
                                                 ushort* __restrict__ out) {
    __shared__ ushort As[BM * BK];
    __shared__ ushort Bs[BN * BK];

    int t = threadIdx.x;
    int row0 = blockIdx.x * BM;
    int col0 = blockIdx.y * BN;

    int lane = t & 63, w = t >> 6;
    int wr = w >> 1, wc = w & 1;
    int l16 = lane & 15, lhi = lane >> 4;

    f32x4 acc[4][4];
#pragma unroll
    for (int m = 0; m < 4; m++)
#pragma unroll
        for (int n = 0; n < 4; n++)
            acc[m][n] = (f32x4){0.f, 0.f, 0.f, 0.f};

    for (int k0 = 0; k0 < K; k0 += BK) {
#pragma unroll
        for (int q = 0; q < 4; q++) {
            int chunk = q * 256 + t;
            int row = chunk >> 3;
            int il = (chunk & 7) ^ (row & 7);
            ASYNC16(A  + (long)(row0 + row) * K + k0 + il * 8, (char*)As + chunk * 16);
            ASYNC16(Wt + (long)(col0 + row) * K + k0 + il * 8, (char*)Bs + chunk * 16);
        }
        __syncthreads();
#pragma unroll
        for (int kk = 0; kk < 2; kk++) {
            bf16x8 af[4], bfr[4];
#pragma unroll
            for (int m = 0; m < 4; m++) {
                int rl = wr * 64 + m * 16 + l16;
                int off = rl * 128 + ((kk * 64 + lhi * 16) ^ ((rl & 7) << 4));
                af[m] = *(const bf16x8*)((const char*)As + off);
            }
#pragma unroll
            for (int n = 0; n < 4; n++) {
                int rl = wc * 64 + n * 16 + l16;
                int off = rl * 128 + ((kk * 64 + lhi * 16) ^ ((rl & 7) << 4));
                bfr[n] = *(const bf16x8*)((const char*)Bs + off);
            }
#pragma unroll
            for (int m = 0; m < 4; m++)
#pragma unroll
                for (int n = 0; n < 4; n++)
                    acc[m][n] = __builtin_amdgcn_mfma_f32_16x16x32_bf16(af[m], bfr[n], acc[m][n], 0, 0, 0);
        }
        __syncthreads();
    }

    float bvn[4];
#pragma unroll
    for (int n = 0; n < 4; n++) {
        int col = col0 + wc * 64 + n * 16 + l16;
        bvn[n] = (col < DHID) ? bl[col] : br[col - DHID];
    }
#pragma unroll
    for (int m = 0; m < 4; m++) {
        int rbase = row0 + wr * 64 + m * 16 + lhi * 4;
#pragma unroll
        for (int j = 0; j < 4; j++) {
            int row = rbase + j;
            if (row < NN) {
#pragma unroll
                for (int n = 0; n < 4; n++) {
                    int col = col0 + wc * 64 + n * 16 + l16;
                    out[(long)row * NLR + col] = f2bf(acc[m][n][j] + bvn[n]);
                }
            }
        }
    }
}

// ---------------- fused per-node logits + softmax + aggregate (+log_softmax) ----------------
// One WAVE per dst node (4 nodes / 256-thr block). Lane owns channels lane*8..+7;
// head = lane>>3 (8 lanes/head, 3-shfl reduce). exp2 domain; log2e folded into att.
// leaky_relu(t) = 0.6t + 0.4|t| (|t| is a free VOP3 modifier).
// Defer-max: rescale only when s - m > 8 (wgt <= 256, f32-safe; acc/d invariant).
// MODE 0: +bias, ELU, write bf16 (h1). MODE 1: +bias, write f32 h2 + fused log_softmax.

#define CVT8(u, f)                                  \
    f[0] = __uint_as_float((u).x << 16);            \
    f[1] = __uint_as_float((u).x & 0xffff0000u);    \
    f[2] = __uint_as_float((u).y << 16);            \
    f[3] = __uint_as_float((u).y & 0xffff0000u);    \
    f[4] = __uint_as_float((u).z << 16);            \
    f[5] = __uint_as_float((u).z & 0xffff0000u);    \
    f[6] = __uint_as_float((u).w << 16);            \
    f[7] = __uint_as_float((u).w & 0xffff0000u);

template <int MODE>
__global__ __launch_bounds__(256) void aggregate_kernel(const ushort* __restrict__ lr,
                                                        const float* __restrict__ att,
                                                        const float* __restrict__ bias,
                                                        const int* __restrict__ csr_src,
                                                        const int* __restrict__ offs,
                                                        ushort* __restrict__ out_bf,
                                                        float* __restrict__ out_f32,
                                                        float* __restrict__ out_lsm) {
    int i = blockIdx.x * 4 + (threadIdx.x >> 6);
    int lane = threadIdx.x & 63;
    int c0 = lane << 3;

    uint4 ur = *(const uint4*)(lr + (long)i * NLR + DHID + c0);
    float rv[8];
    CVT8(ur, rv);
    float a06[8], a04[8];
    float4 at0 = *(const float4*)&att[c0];
    float4 at1 = *(const float4*)&att[c0 + 4];
    const float K06 = 0.6f * 1.44269504f, K04 = 0.4f * 1.44269504f;
    a06[0] = at0.x * K06; a06[1] = at0.y * K06; a06[2] = at0.z * K06; a06[3] = at0.w * K06;
    a06[4] = at1.x * K06; a06[5] = at1.y * K06; a06[6] = at1.z * K06; a06[7] = at1.w * K06;
    a04[0] = at0.x * K04; a04[1] = at0.y * K04; a04[2] = at0.z * K04; a04[3] = at0.w * K04;
    a04[4] = at1.x * K04; a04[5] = at1.y * K04; a04[6] = at1.z * K04; a04[7] = at1.w * K04;

    int beg = offs[i], end = offs[i + 1];
    float m = -3.0e38f, d = 0.f;
    float acc[8] = {0.f, 0.f, 0.f, 0.f, 0.f, 0.f, 0.f, 0.f};

    int j = csr_src[beg];
    uint4 v = *(const uint4*)(lr + (long)j * NLR + c0);

    for (int k = beg; k < end; k++) {
        uint4 vc = v;
        int jn = csr_src[k + 1];  // safe over-read: next node's entry / count[0]
        v = *(const uint4*)(lr + (long)jn * NLR + c0);

        float lx[8];
        CVT8(vc, lx);
        float s = 0.f;
#pragma unroll
        for (int c = 0; c < 8; c++) {
            float tt = lx[c] + rv[c];
            s = fmaf(a06[c], tt, s);
            s = fmaf(a04[c], __builtin_fabsf(tt), s);  // abs folds to VOP3 modifier
        }
        s += __shfl_xor(s, 1);
        s += __shfl_xor(s, 2);
        s += __shfl_xor(s, 4);

        float delta = s - m;
        if (__builtin_expect(delta > 8.f, 0)) {   // rare: first edge + big jumps
            float sc = exp2f(-delta);
            d *= sc;
#pragma unroll
            for (int c = 0; c < 8; c++) acc[c] *= sc;
            m = s;
            delta = 0.f;
        }
        float wgt = exp2f(delta);
        d += wgt;
#pragma unroll
        for (int c = 0; c < 8; c++) acc[c] = fmaf(wgt, lx[c], acc[c]);
    }

    float inv = 1.f / d;
    float o[8];
    float4 bi0 = *(const float4*)&bias[c0];
    float4 bi1 = *(const float4*)&bias[c0 + 4];
    o[0] = fmaf(acc[0], inv, bi0.x); o[1] = fmaf(acc[1], inv, bi0.y);
    o[2] = fmaf(acc[2], inv, bi0.z); o[3] = fmaf(acc[3], inv, bi0.w);
    o[4] = fmaf(acc[4], inv, bi1.x); o[5] = fmaf(acc[5], inv, bi1.y);
    o[6] = fmaf(acc[6], inv, bi1.z); o[7] = fmaf(acc[7], inv, bi1.w);

    if (MODE == 0) {
#pragma unroll
        for (int c = 0; c < 8; c++) o[c] = (o[c] > 0.f) ? o[c] : expm1f(o[c]);
        uint4 p;
        p.x = (uint)f2bf(o[0]) | ((uint)f2bf(o[1]) << 16);
        p.y = (uint)f2bf(o[2]) | ((uint)f2bf(o[3]) << 16);
        p.z = (uint)f2bf(o[4]) | ((uint)f2bf(o[5]) << 16);
        p.w = (uint)f2bf(o[6]) | ((uint)f2bf(o[7]) << 16);
        *(uint4*)(out_bf + (long)i * DHID + c0) = p;
    } else {
        // write h2
        *(float4*)&out_f32[(long)i * DHID + c0]     = *(float4*)&o[0];
        *(float4*)&out_f32[(long)i * DHID + c0 + 4] = *(float4*)&o[4];
        // fused log_softmax over the 512-wide row held by this wave
        float mx = o[0];
#pragma unroll
        for (int c = 1; c < 8; c++) mx = fmaxf(mx, o[c]);
#pragma unroll
        for (int off = 1; off < 64; off <<= 1) mx = fmaxf(mx, __shfl_xor(mx, off));
        float se = 0.f;
#pragma unroll
        for (int c = 0; c < 8; c++) se += __expf(o[c] - mx);
#pragma unroll
        for (int off = 1; off < 64; off <<= 1) se += __shfl_xor(se, off);
        float lg = mx + logf(se);
        float l0[8];
#pragma unroll
        for (int c = 0; c < 8; c++) l0[c] = o[c] - lg;
        *(float4*)&out_lsm[(long)i * DHID + c0]     = *(float4*)&l0[0];
        *(float4*)&out_lsm[(long)i * DHID + c0 + 4] = *(float4*)&l0[4];
    }
}

// ---------------- launch ----------------

extern "C" void kernel_launch(void* const* d_in, const int* in_sizes, int n_in,
                              void* d_out, int out_size, void* d_ws, size_t ws_size,
                              hipStream_t stream) {
    const float* x     = (const float*)d_in[0];
    const int*   ei    = (const int*)d_in[1];
    const float* Wl1   = (const float*)d_in[2];
    const float* bl1   = (const float*)d_in[3];
    const float* Wr1   = (const float*)d_in[4];
    const float* br1   = (const float*)d_in[5];
    const float* att1  = (const float*)d_in[6];
    const float* bias1 = (const float*)d_in[7];
    const float* Wl2   = (const float*)d_in[8];
    const float* bl2   = (const float*)d_in[9];
    const float* Wr2   = (const float*)d_in[10];
    const float* br2   = (const float*)d_in[11];
    const float* att2  = (const float*)d_in[12];
    const float* bias2 = (const float*)d_in[13];

    float* out = (float*)d_out;
    float* h2  = out;                      // final layer-2 output [NN,512] f32
    float* lsm = out + (long)NN * DHID;    // log_softmax area

    ushort* lrbuf  = (ushort*)d_ws;                      // [NN,1024] bf16
    ushort* Abf    = lrbuf + (long)NN * NLR;             // [MPAD,512] bf16
    ushort* Wt1    = Abf + (long)MPAD * DHID;            // [1024,256] bf16
    ushort* Wt2    = Wt1 + (long)NLR * D_IN;             // [1024,512] bf16
    int*    csr_src = (int*)(Wt2 + (long)NLR * DHID);    // ET
    int*    count   = csr_src + ET;                      // NN
    int*    offs    = count + NN;                        // NN+1
    int*    cursor  = offs + NN + 1;                     // NN

    const int* srcv = ei;
    const int* dstv = ei + NE;

    convert_x<<<(MPAD * D_IN / 4 + 255) / 256, 256, 0, stream>>>(x, Abf);
    zero_pad2<<<((MPAD - NN) * DHID / 4 + 255) / 256, 256, 0, stream>>>(Abf);
    transpose_w<<<dim3(D_IN / 32, NLR / 32), 256, 0, stream>>>(Wl1, Wr1, Wt1, D_IN);
    transpose_w<<<dim3(DHID / 32, NLR / 32), 256, 0, stream>>>(Wl2, Wr2, Wt2, DHID);

    init_count<<<(NN + 255) / 256, 256, 0, stream>>>(count);
    hist_kernel<<<(NE + 255) / 256, 256, 0, stream>>>(dstv, count);
    scan_kernel<<<1, 1024, 0, stream>>>(count, offs, cursor);
    scatter_kernel<<<(ET + 255) / 256, 256, 0, stream>>>(srcv, dstv, cursor, csr_src);

    dim3 ggrid((NN + BM - 1) / BM, NLR / BN);

    // layer 1
    gemm_mfma<<<ggrid, 256, 0, stream>>>(Abf, D_IN, Wt1, bl1, br1, lrbuf);
    aggregate_kernel<0><<<NN / 4, 256, 0, stream>>>(lrbuf, att1, bias1, csr_src, offs, Abf, nullptr, nullptr);

    // layer 2 (log_softmax fused into the aggregate epilogue)
    gemm_mfma<<<ggrid, 256, 0, stream>>>(Abf, DHID, Wt2, bl2, br2, lrbuf);
    aggregate_kernel<1><<<NN / 4, 256, 0, stream>>>(lrbuf, att2, bias2, csr_src, offs, nullptr, h2, lsm);
}